// Round 2
// baseline (303.227 us; speedup 1.0000x reference)
//
#include <hip/hip_runtime.h>
#include <hip/hip_bf16.h>
#include <hip/hip_fp16.h>
#include <stdint.h>
#include <stddef.h>
#include <string.h>

#define D_EMB 1024
#define SEQ   2048
#define BATCH 4

typedef short bf16x8  __attribute__((ext_vector_type(8)));
typedef short short8  __attribute__((ext_vector_type(8)));
typedef float f32x4   __attribute__((ext_vector_type(4)));

#define AS1 __attribute__((address_space(1)))
#define AS3 __attribute__((address_space(3)))

static __device__ __forceinline__ void async_copy16(const void* g, void* l) {
  __builtin_amdgcn_global_load_lds((const AS1 void*)g, (AS3 void*)l, 16, 0, 0);
}

// ============================================================================
// 256^2-tile 8-phase GEMM core (verified R1: 922 TF machine-rate, 0 bank
// conflicts, passed). R2 adds a PERSISTENT variant for qkv: 2 output tiles
// per block sharing one M-panel, continuous K-stream (32 k-tiles), mid-stream
// accumulator store at the tile boundary. Head/tail overhead (prologue burst +
// epilogue drain, ~15-20us/tile at K=1024) is paid once per block, not per
// tile, and 192 blocks x 2 tiles packs 384 tiles with zero imbalance.
// ============================================================================

#define BAR     __builtin_amdgcn_s_barrier()
#define VMCNT4  asm volatile("s_waitcnt vmcnt(4)" ::: "memory")
#define VMCNT0  asm volatile("s_waitcnt vmcnt(0)" ::: "memory")

// ---- original fixed-source staging (used by gemm256 for scores/pv) ----
#define STAGE_A(buf, h, kt) do {                                              \
    const __hip_bfloat16* _g = gA + (size_t)((h) * 128) * lda + ((kt) << 6);  \
    char* _l = (char*)sA + (buf) * 32768 + (h) * 16384 + wave * 1024;         \
    async_copy16(_g, _l);                                                     \
    async_copy16(_g + (size_t)64 * lda, _l + 8192);                           \
  } while (0)
#define STAGE_B(buf, h, kt) do {                                              \
    const __hip_bfloat16* _g = gB + (size_t)((h) * 128) * ldb + ((kt) << 6);  \
    char* _l = (char*)sB + (buf) * 32768 + (h) * 16384 + wave * 1024;         \
    async_copy16(_g, _l);                                                     \
    async_copy16(_g + (size_t)64 * ldb, _l + 8192);                           \
  } while (0)

// ---- parameterized staging for the persistent qkv stream (ld = D_EMB) ----
#define STAGE_P(dst, buf, h, gbase, kc) do {                                   \
    const __hip_bfloat16* _g = (gbase) + (size_t)((h) * 128) * D_EMB + (kc);   \
    char* _l = (char*)(dst) + (buf) * 32768 + (h) * 16384 + wave * 1024;       \
    async_copy16(_g, _l);                                                      \
    async_copy16(_g + (size_t)64 * D_EMB, _l + 8192);                          \
  } while (0)

// quadrant fragment loads (row&7 == lr&7 for all frag rows -> pc0/pc1 fixed)
#define LOAD_A(aF, lbuf, h) do {                                              \
    const __hip_bfloat16* _b = (lbuf) + (wr * 128 + (h) * 64 + lr) * 64;      \
    _Pragma("unroll")                                                         \
    for (int _i = 0; _i < 4; _i++) {                                          \
      aF[_i][0] = *(const bf16x8*)&_b[_i * 1024 + pc0];                       \
      aF[_i][1] = *(const bf16x8*)&_b[_i * 1024 + pc1];                       \
    }                                                                         \
  } while (0)
#define LOAD_B(bF, lbuf, g) do {                                              \
    const __hip_bfloat16* _b = (lbuf) + (wc * 64 + (g) * 32 + lr) * 64;       \
    _Pragma("unroll")                                                         \
    for (int _j = 0; _j < 2; _j++) {                                          \
      bF[_j][0] = *(const bf16x8*)&_b[_j * 1024 + pc0];                       \
      bF[_j][1] = *(const bf16x8*)&_b[_j * 1024 + pc1];                       \
    }                                                                         \
  } while (0)

#define MFMA_Q(aF, bF, h, g) do {                                             \
    __builtin_amdgcn_s_setprio(1);                                            \
    _Pragma("unroll")                                                         \
    for (int _i = 0; _i < 4; _i++)                                            \
      _Pragma("unroll")                                                       \
      for (int _j = 0; _j < 2; _j++) {                                        \
        acc[(h) * 4 + _i][(g) * 2 + _j] =                                     \
          __builtin_amdgcn_mfma_f32_16x16x32_bf16(aF[_i][0], bF[_j][0],       \
              acc[(h) * 4 + _i][(g) * 2 + _j], 0, 0, 0);                      \
        acc[(h) * 4 + _i][(g) * 2 + _j] =                                     \
          __builtin_amdgcn_mfma_f32_16x16x32_bf16(aF[_i][1], bF[_j][1],       \
              acc[(h) * 4 + _i][(g) * 2 + _j], 0, 0, 0);                      \
      }                                                                       \
    __builtin_amdgcn_s_setprio(0);                                            \
  } while (0)

#define ZERO_ACC(acc)                         \
  {                                           \
    f32x4 _z = {0.f, 0.f, 0.f, 0.f};          \
    _Pragma("unroll")                         \
    for (int _i = 0; _i < 8; _i++)            \
      _Pragma("unroll")                       \
      for (int _j = 0; _j < 4; _j++)          \
        acc[_i][_j] = _z;                     \
  }

static __device__ __forceinline__ void gemm256(
    const __hip_bfloat16* __restrict__ A, int lda,
    const __hip_bfloat16* __restrict__ Bt, int ldb,
    int K, f32x4 (&acc)[8][4])
{
  __shared__ __hip_bfloat16 sA[2][128 * 64 * 2];   // 64 KiB
  __shared__ __hip_bfloat16 sB[2][128 * 64 * 2];   // 64 KiB

  const int t    = threadIdx.x;   // 0..511
  const int wave = t >> 6;        // 0..7
  const int lane = t & 63;
  const int quad = lane >> 4;
  const int lr   = lane & 15;
  const int wr   = wave >> 2;     // 0..1  (M)
  const int wc   = wave & 3;      // 0..3  (N)

  const int r0 = t >> 3;                         // 0..63
  const int cs = (((t & 7) ^ (r0 & 7)) << 3);    // swizzled source column
  const __hip_bfloat16* gA = A  + (size_t)r0 * lda + cs;
  const __hip_bfloat16* gB = Bt + (size_t)r0 * ldb + cs;

  const int pc0 = ((quad)     ^ (lr & 7)) << 3;
  const int pc1 = ((quad + 4) ^ (lr & 7)) << 3;

  const __hip_bfloat16* const lA0 = sA[0];
  const __hip_bfloat16* const lA1 = sA[1];
  const __hip_bfloat16* const lB0 = sB[0];
  const __hip_bfloat16* const lB1 = sB[1];

  const int nt    = K >> 6;
  const int niter = nt >> 1;

  STAGE_A(0, 0, 0);
  STAGE_A(0, 1, 0);
  STAGE_B(0, 0, 0);
  STAGE_B(0, 1, 0);
  STAGE_A(1, 0, 1);
  STAGE_B(1, 1, 1);
  VMCNT4;
  BAR;

  bf16x8 aF[4][2], bFa[2][2], bFb[2][2];

  for (int j = 0; j < niter - 1; ++j) {
    const int tb = 2 * j + 1, tc = tb + 1, td = tb + 2;

    LOAD_A(aF, lA0, 0); LOAD_B(bFa, lB0, 0);
    STAGE_B(1, 0, tb);
    BAR; MFMA_Q(aF, bFa, 0, 0); BAR;

    LOAD_B(bFb, lB0, 1);
    STAGE_A(1, 1, tb);
    BAR; MFMA_Q(aF, bFb, 0, 1); BAR;

    LOAD_A(aF, lA0, 1);
    STAGE_A(0, 0, tc);
    BAR; MFMA_Q(aF, bFb, 1, 1); BAR;

    STAGE_B(0, 1, tc);
    VMCNT4;
    BAR; MFMA_Q(aF, bFa, 1, 0); BAR;

    LOAD_A(aF, lA1, 0); LOAD_B(bFa, lB1, 0);
    STAGE_B(0, 0, tc);
    BAR; MFMA_Q(aF, bFa, 0, 0); BAR;

    LOAD_B(bFb, lB1, 1);
    STAGE_A(0, 1, tc);
    BAR; MFMA_Q(aF, bFb, 0, 1); BAR;

    LOAD_A(aF, lA1, 1);
    STAGE_A(1, 0, td);
    BAR; MFMA_Q(aF, bFb, 1, 1); BAR;

    STAGE_B(1, 1, td);
    VMCNT4;
    BAR; MFMA_Q(aF, bFa, 1, 0); BAR;
  }

  {
    const int tb = nt - 1;
    LOAD_A(aF, lA0, 0); LOAD_B(bFa, lB0, 0);
    STAGE_B(1, 0, tb);
    BAR; MFMA_Q(aF, bFa, 0, 0); BAR;

    LOAD_B(bFb, lB0, 1);
    STAGE_A(1, 1, tb);
    BAR; MFMA_Q(aF, bFb, 0, 1); BAR;

    LOAD_A(aF, lA0, 1);
    BAR; MFMA_Q(aF, bFb, 1, 1); BAR;

    VMCNT0;
    BAR; MFMA_Q(aF, bFa, 1, 0); BAR;

    LOAD_A(aF, lA1, 0); LOAD_B(bFa, lB1, 0);
    BAR; MFMA_Q(aF, bFa, 0, 0); BAR;

    LOAD_B(bFb, lB1, 1);
    BAR; MFMA_Q(aF, bFb, 0, 1); BAR;

    LOAD_A(aF, lA1, 1);
    BAR; MFMA_Q(aF, bFb, 1, 1); BAR;

    MFMA_Q(aF, bFa, 1, 0);
  }
}

// ---------------- fused prep: z<3 -> transpose+cast W; z==3 -> cast x ----------------
__global__ __launch_bounds__(256) void prep_kernel(
    const float* __restrict__ x,
    const float* __restrict__ Wq,
    const float* __restrict__ Wk,
    const float* __restrict__ Wv,
    __hip_bfloat16* __restrict__ xb,
    __hip_bfloat16* __restrict__ Wt3)
{
  const int tx = threadIdx.x, ty = threadIdx.y;  // (32,8)
  if (blockIdx.z == 3) {
    const int tid = ty * 32 + tx;
    const size_t base = ((size_t)blockIdx.y * 32 + blockIdx.x) * 8192;
#pragma unroll
    for (int p = 0; p < 8; p++) {
      const size_t i = base + p * 1024 + tid * 4;
      const float4 v = *(const float4*)(x + i);
      __hip_bfloat16 o[4] = {__float2bfloat16(v.x), __float2bfloat16(v.y),
                             __float2bfloat16(v.z), __float2bfloat16(v.w)};
      *(uint64_t*)(xb + i) = *(uint64_t*)o;
    }
    return;
  }
  const float* src = (blockIdx.z == 0) ? Wq : (blockIdx.z == 1) ? Wk : Wv;
  __hip_bfloat16* dst = Wt3 + (size_t)blockIdx.z * D_EMB * D_EMB;
  __shared__ __hip_bfloat16 tile[32][33];
  const int x0 = blockIdx.x * 32;  // e
  const int y0 = blockIdx.y * 32;  // d
#pragma unroll
  for (int i = 0; i < 32; i += 8)
    tile[ty + i][tx] = __float2bfloat16(src[(size_t)(y0 + ty + i) * D_EMB + (x0 + tx)]);
  __syncthreads();
#pragma unroll
  for (int i = 0; i < 32; i += 8)
    dst[(size_t)(x0 + ty + i) * D_EMB + (y0 + tx)] = tile[tx][ty + i];
}

// ---------------- qkv mid/final tile store ----------------
// col in 0..11: mat = col>>2 (0=Q,1=K,2=V), n0 = (col&3)*256.
static __device__ __forceinline__ void qkv_store(
    f32x4 (&acc)[8][4], int col, int m0,
    const float* __restrict__ bq, const float* __restrict__ bk,
    const float* __restrict__ bv,
    __hip_bfloat16* __restrict__ Q, __hip_bfloat16* __restrict__ Kb,
    __hip_bfloat16* __restrict__ Vt, int t)
{
  const int mat = col >> 2;
  const int n0  = (col & 3) << 8;
  const float* bias = (mat == 0) ? bq : (mat == 1) ? bk : bv;
  const int wave = t >> 6, lane = t & 63;
  const int quad = lane >> 4, lr = lane & 15;
  const int wr = wave >> 2, wc = wave & 3;
#pragma unroll
  for (int i = 0; i < 8; i++) {
#pragma unroll
    for (int j = 0; j < 4; j++) {
      const int n = n0 + wc * 64 + j * 16 + lr;
      const float bb = bias[n];
      const int mbase = m0 + wr * 128 + i * 16 + quad * 4;
      if (mat == 2) {
        // Vt[b][n][s], s = mbase..mbase+3 contiguous -> one 8B store
        const int b = mbase >> 11, s = mbase & 2047;
        __hip_bfloat16 pk[4];
#pragma unroll
        for (int r = 0; r < 4; r++) pk[r] = __float2bfloat16(acc[i][j][r] + bb);
        *(uint64_t*)&Vt[(size_t)b * D_EMB * SEQ + (size_t)n * SEQ + s] = *(uint64_t*)pk;
      } else {
        __hip_bfloat16* dst = (mat == 0) ? Q : Kb;
#pragma unroll
        for (int r = 0; r < 4; r++)
          dst[(size_t)(mbase + r) * D_EMB + n] = __float2bfloat16(acc[i][j][r] + bb);
      }
    }
  }
}

// ---------------- QKV projections: persistent 2-tile stream ----------------
// One logical GEMM 8192 x 3072 x 1024 (Wt3 = Wq|Wk|Wv rows are contiguous).
// 192 blocks = 32 m-panels x 6 col-pairs; block (m, c) computes output tiles
// (m, c) then (m, c+6) as ONE continuous 32-k-tile 8-phase stream: A addresses
// repeat (same M-panel -> 2nd pass L2-hot), B base switches at k-tile 16.
// Mid-stream store after k-pair j=7; ledger never drains across the boundary
// (j=7 p8 vmcnt(4) completes buf0/k16 exactly before the store).
// id%8 = m%8 -> same-m blocks pinned per XCD (A-panel L2 locality).
__global__ __launch_bounds__(512, 2) void qkv_kernel(
    const __hip_bfloat16* __restrict__ xb,
    const __hip_bfloat16* __restrict__ Wt3,
    const float* __restrict__ bq,
    const float* __restrict__ bk,
    const float* __restrict__ bv,
    __hip_bfloat16* __restrict__ Q,
    __hip_bfloat16* __restrict__ Kb,
    __hip_bfloat16* __restrict__ Vt)
{
  __shared__ __hip_bfloat16 sA[2][128 * 64 * 2];   // 64 KiB
  __shared__ __hip_bfloat16 sB[2][128 * 64 * 2];   // 64 KiB

  const int t    = threadIdx.x;
  const int wave = t >> 6;
  const int lane = t & 63;
  const int quad = lane >> 4;
  const int lr   = lane & 15;
  const int wr   = wave >> 2;
  const int wc   = wave & 3;

  const int m0   = blockIdx.x * 256;   // M-panel (shared by both tiles)
  const int col0 = blockIdx.y;         // 0..5; tiles col0 and col0+6

  const int r0 = t >> 3;
  const int cs = (((t & 7) ^ (r0 & 7)) << 3);
  const __hip_bfloat16* gA  = xb + (size_t)m0 * D_EMB + (size_t)r0 * D_EMB + cs;
  const __hip_bfloat16* gB0 = Wt3 + ((size_t)col0 << 18) + (size_t)r0 * D_EMB + cs;
  const __hip_bfloat16* gB1 = gB0 + ((size_t)6 << 18);

  const int pc0 = ((quad)     ^ (lr & 7)) << 3;
  const int pc1 = ((quad + 4) ^ (lr & 7)) << 3;

  const __hip_bfloat16* const lA0 = sA[0];
  const __hip_bfloat16* const lA1 = sA[1];
  const __hip_bfloat16* const lB0 = sB[0];
  const __hip_bfloat16* const lB1 = sB[1];

  f32x4 acc[8][4];
  ZERO_ACC(acc);

  // prologue: k-tile 0 complete + A-lo(1), B-hi(1)
  STAGE_P(sA, 0, 0, gA,  0);
  STAGE_P(sA, 0, 1, gA,  0);
  STAGE_P(sB, 0, 0, gB0, 0);
  STAGE_P(sB, 0, 1, gB0, 0);
  STAGE_P(sA, 1, 0, gA,  64);
  STAGE_P(sB, 1, 1, gB0, 64);
  VMCNT4;
  BAR;

  bf16x8 aF[4][2], bFa[2][2], bFb[2][2];

  // 32 global k-tiles, pairs j = 0..15; main loop j<15, final pair peeled.
  for (int j = 0; j < 15; ++j) {
    const int tb = 2 * j + 1, tc = tb + 1, td = tb + 2;
    const __hip_bfloat16* bTb = (tb & 16) ? gB1 : gB0;
    const __hip_bfloat16* bTc = (tc & 16) ? gB1 : gB0;
    const __hip_bfloat16* bTd = (td & 16) ? gB1 : gB0;
    const int kb  = (tb & 15) << 6;
    const int kc2 = (tc & 15) << 6;
    const int kd  = (td & 15) << 6;

    LOAD_A(aF, lA0, 0); LOAD_B(bFa, lB0, 0);
    STAGE_P(sB, 1, 0, bTb, kb);
    BAR; MFMA_Q(aF, bFa, 0, 0); BAR;

    LOAD_B(bFb, lB0, 1);
    STAGE_P(sA, 1, 1, gA, kb);
    BAR; MFMA_Q(aF, bFb, 0, 1); BAR;

    LOAD_A(aF, lA0, 1);
    STAGE_P(sA, 0, 0, gA, kc2);
    BAR; MFMA_Q(aF, bFb, 1, 1); BAR;

    STAGE_P(sB, 0, 1, bTc, kc2);
    VMCNT4;
    BAR; MFMA_Q(aF, bFa, 1, 0); BAR;

    LOAD_A(aF, lA1, 0); LOAD_B(bFa, lB1, 0);
    STAGE_P(sB, 0, 0, bTc, kc2);
    BAR; MFMA_Q(aF, bFa, 0, 0); BAR;

    LOAD_B(bFb, lB1, 1);
    STAGE_P(sA, 0, 1, gA, kc2);
    BAR; MFMA_Q(aF, bFb, 0, 1); BAR;

    LOAD_A(aF, lA1, 1);
    STAGE_P(sA, 1, 0, gA, kd);
    BAR; MFMA_Q(aF, bFb, 1, 1); BAR;

    STAGE_P(sB, 1, 1, bTd, kd);
    VMCNT4;
    BAR; MFMA_Q(aF, bFa, 1, 0); BAR;

    if (j == 7) {
      // tile 0 (col0) complete; store + reset while the ledger keeps flowing.
      qkv_store(acc, col0, m0, bq, bk, bv, Q, Kb, Vt, t);
      ZERO_ACC(acc);
    }
  }

  { // final pair: k-tiles 30 (buf0), 31 (buf1)
    LOAD_A(aF, lA0, 0); LOAD_B(bFa, lB0, 0);
    STAGE_P(sB, 1, 0, gB1, 15 << 6);
    BAR; MFMA_Q(aF, bFa, 0, 0); BAR;

    LOAD_B(bFb, lB0, 1);
    STAGE_P(sA, 1, 1, gA, 15 << 6);
    BAR; MFMA_Q(aF, bFb, 0, 1); BAR;

    LOAD_A(aF, lA0, 1);
    BAR; MFMA_Q(aF, bFb, 1, 1); BAR;

    VMCNT0;
    BAR; MFMA_Q(aF, bFa, 1, 0); BAR;

    LOAD_A(aF, lA1, 0); LOAD_B(bFa, lB1, 0);
    BAR; MFMA_Q(aF, bFa, 0, 0); BAR;

    LOAD_B(bFb, lB1, 1);
    BAR; MFMA_Q(aF, bFb, 0, 1); BAR;

    LOAD_A(aF, lA1, 1);
    BAR; MFMA_Q(aF, bFb, 1, 1); BAR;

    MFMA_Q(aF, bFa, 1, 0);
  }

  qkv_store(acc, col0 + 6, m0, bq, bk, bv, Q, Kb, Vt, t);
}

// ---------------- scores = Q @ K^T * scale (fp16 out) ----------------
__global__ __launch_bounds__(512, 2) void scores_kernel(
    const __hip_bfloat16* __restrict__ Q,
    const __hip_bfloat16* __restrict__ Kb,
    __half* __restrict__ Sc)
{
  const int b  = blockIdx.z;
  const int m0 = blockIdx.y * 256;  // s_q
  const int n0 = blockIdx.x * 256;  // s_k

  f32x4 acc[8][4];
  ZERO_ACC(acc);

  gemm256(Q  + (size_t)b * SEQ * D_EMB + (size_t)m0 * D_EMB, D_EMB,
          Kb + (size_t)b * SEQ * D_EMB + (size_t)n0 * D_EMB, D_EMB,
          D_EMB, acc);

  __half* out = Sc + (size_t)b * SEQ * SEQ;
  const float scale = 0.03125f;  // 1/sqrt(1024)

  const int t = threadIdx.x;
  const int wave = t >> 6, lane = t & 63;
  const int quad = lane >> 4, lr = lane & 15;
  const int wr = wave >> 2, wc = wave & 3;

#pragma unroll
  for (int i = 0; i < 8; i++)
#pragma unroll
    for (int j = 0; j < 4; j++) {
      const int n = n0 + wc * 64 + j * 16 + lr;
#pragma unroll
      for (int r = 0; r < 4; r++) {
        const int m = m0 + wr * 128 + i * 16 + quad * 4 + r;
        out[(size_t)m * SEQ + n] = __float2half(acc[i][j][r] * scale);
      }
    }
}

// ---------------- row softmax: fp16 scores -> bf16 probs (16B vectorized) ----------------
__global__ __launch_bounds__(256) void softmax_kernel(
    const __half* __restrict__ Sc, __hip_bfloat16* __restrict__ P)
{
  const int row = blockIdx.x;  // 0..8191
  const __half* src = Sc + (size_t)row * SEQ;
  const int t = threadIdx.x;
  const int wave = t >> 6, lane = t & 63;

  const short8 raw = *(const short8*)(src + t * 8);
  float v[8];
#pragma unroll
  for (int i = 0; i < 8; i++) {
    const short si = raw[i];
    __half h;
    memcpy(&h, &si, sizeof(h));
    v[i] = __half2float(h);
  }

  float m = v[0];
#pragma unroll
  for (int i = 1; i < 8; i++) m = fmaxf(m, v[i]);
#pragma unroll
  for (int o = 32; o > 0; o >>= 1) m = fmaxf(m, __shfl_xor(m, o));

  __shared__ float redm[4];
  __shared__ float reds[4];
  if (lane == 0) redm[wave] = m;
  __syncthreads();
  m = fmaxf(fmaxf(redm[0], redm[1]), fmaxf(redm[2], redm[3]));

  float e[8], s = 0.f;
#pragma unroll
  for (int i = 0; i < 8; i++) { e[i] = __expf(v[i] - m); s += e[i]; }
#pragma unroll
  for (int o = 32; o > 0; o >>= 1) s += __shfl_xor(s, o);
  if (lane == 0) reds[wave] = s;
  __syncthreads();
  s = reds[0] + reds[1] + reds[2] + reds[3];

  const float inv = 1.f / s;
  short8 outp;
#pragma unroll
  for (int i = 0; i < 8; i++) {
    const __hip_bfloat16 b = __float2bfloat16(e[i] * inv);
    short sb;
    memcpy(&sb, &b, sizeof(sb));
    outp[i] = sb;
  }
  *(short8*)(P + (size_t)row * SEQ + t * 8) = outp;
}

// ---------------- out(fp32) = P @ V  (A = probs [sq][sk], Bt = Vt [e][sk]) ----------------
__global__ __launch_bounds__(512, 2) void pv_kernel(
    const __hip_bfloat16* __restrict__ P,
    const __hip_bfloat16* __restrict__ Vt,
    float* __restrict__ out)
{
  const int b  = blockIdx.z;
  const int m0 = blockIdx.y * 256;  // s_q
  const int n0 = blockIdx.x * 256;  // e

  f32x4 acc[8][4];
  ZERO_ACC(acc);

  gemm256(P  + (size_t)b * SEQ * SEQ   + (size_t)m0 * SEQ, SEQ,
          Vt + (size_t)b * D_EMB * SEQ + (size_t)n0 * SEQ, SEQ,
          SEQ, acc);

  float* o = out + (size_t)b * SEQ * D_EMB;

  const int t = threadIdx.x;
  const int wave = t >> 6, lane = t & 63;
  const int quad = lane >> 4, lr = lane & 15;
  const int wr = wave >> 2, wc = wave & 3;

#pragma unroll
  for (int i = 0; i < 8; i++)
#pragma unroll
    for (int j = 0; j < 4; j++) {
      const int n = n0 + wc * 64 + j * 16 + lr;
#pragma unroll
      for (int r = 0; r < 4; r++) {
        const int m = m0 + wr * 128 + i * 16 + quad * 4 + r;
        o[(size_t)m * D_EMB + n] = acc[i][j][r];
      }
    }
}

extern "C" void kernel_launch(void* const* d_in, const int* in_sizes, int n_in,
                              void* d_out, int out_size, void* d_ws, size_t ws_size,
                              hipStream_t stream) {
  const float* x  = (const float*)d_in[0];
  const float* Wq = (const float*)d_in[1];
  const float* bq = (const float*)d_in[2];
  const float* Wk = (const float*)d_in[3];
  const float* bk = (const float*)d_in[4];
  const float* Wv = (const float*)d_in[5];
  const float* bv = (const float*)d_in[6];
  float* out = (float*)d_out;

  char* ws = (char*)d_ws;
  __hip_bfloat16* xb  = (__hip_bfloat16*)(ws);
  __hip_bfloat16* Wt3 = (__hip_bfloat16*)(ws + 16777216);
  __hip_bfloat16* Q   = (__hip_bfloat16*)(ws + 23068672);
  __hip_bfloat16* Kb  = (__hip_bfloat16*)(ws + 39845888);
  __hip_bfloat16* Vt  = (__hip_bfloat16*)(ws + 56623104);
  __half*         Sc  = (__half*)        (ws + 73400320);   // 32 MB fp16
  __hip_bfloat16* P   = (__hip_bfloat16*)(ws + 140509184);
  // total = 140509184 + 33554432 = 174,063,616 bytes (~166 MB)

  prep_kernel  <<<dim3(32, 32, 4), dim3(32, 8), 0, stream>>>(x, Wq, Wk, Wv, xb, Wt3);
  qkv_kernel   <<<dim3(32, 6, 1),  512,        0, stream>>>(xb, Wt3, bq, bk, bv, Q, Kb, Vt);
  scores_kernel<<<dim3(8, 8, 4),   512,        0, stream>>>(Q, Kb, Sc);
  softmax_kernel<<<dim3(8192),     256,        0, stream>>>(Sc, P);
  pv_kernel    <<<dim3(4, 8, 4),   512,        0, stream>>>(P, Vt, out);
}

// Round 3
// 267.266 us; speedup vs baseline: 1.1346x; 1.1346x over previous
//
#include <hip/hip_runtime.h>
#include <hip/hip_bf16.h>
#include <hip/hip_fp16.h>
#include <stdint.h>
#include <stddef.h>
#include <string.h>

#define D_EMB 1024
#define SEQ   2048
#define BATCH 4

typedef short bf16x8  __attribute__((ext_vector_type(8)));
typedef short short8  __attribute__((ext_vector_type(8)));
typedef float f32x4   __attribute__((ext_vector_type(4)));

#define AS1 __attribute__((address_space(1)))
#define AS3 __attribute__((address_space(3)))

static __device__ __forceinline__ void async_copy16(const void* g, void* l) {
  __builtin_amdgcn_global_load_lds((const AS1 void*)g, (AS3 void*)l, 16, 0, 0);
}

// ============================================================================
// 8-phase 256-wide GEMM cores.
//  gemm256    : 256x256 tile (verified R1: 922 TF round-rate, 0 conflicts).
//  gemm256x128: 256x128 tile, SAME phase/barrier/ledger structure, B-half is
//               1 copy/thread -> counted wait is vmcnt(3). For pv (K=2048,
//               needs 256 blocks to fill the machine; 256x256 gave only 128).
// R2 LESSON (counters): mid-loop accumulator store => 79 MB scratch spill
// (WRITE 49->128 MB), MfmaUtil 26->20. Persistent multi-tile streams are off
// the table; per-tile kernels only.
// ============================================================================

#define BAR     __builtin_amdgcn_s_barrier()
#define VMCNT4  asm volatile("s_waitcnt vmcnt(4)" ::: "memory")
#define VMCNT3  asm volatile("s_waitcnt vmcnt(3)" ::: "memory")
#define VMCNT0  asm volatile("s_waitcnt vmcnt(0)" ::: "memory")

#define STAGE_A(buf, h, kt) do {                                              \
    const __hip_bfloat16* _g = gA + (size_t)((h) * 128) * lda + ((kt) << 6);  \
    char* _l = (char*)sA + (buf) * 32768 + (h) * 16384 + wave * 1024;         \
    async_copy16(_g, _l);                                                     \
    async_copy16(_g + (size_t)64 * lda, _l + 8192);                           \
  } while (0)
#define STAGE_B(buf, h, kt) do {                                              \
    const __hip_bfloat16* _g = gB + (size_t)((h) * 128) * ldb + ((kt) << 6);  \
    char* _l = (char*)sB + (buf) * 32768 + (h) * 16384 + wave * 1024;         \
    async_copy16(_g, _l);                                                     \
    async_copy16(_g + (size_t)64 * ldb, _l + 8192);                           \
  } while (0)
// B-half for the x128 variant: 64 rows = exactly 512 threads * 16B = 1 copy.
#define STAGE_B1(buf, h, kt) do {                                             \
    const __hip_bfloat16* _g = gB + (size_t)((h) * 64) * ldb + ((kt) << 6);   \
    char* _l = (char*)sB + (buf) * 16384 + (h) * 8192 + wave * 1024;          \
    async_copy16(_g, _l);                                                     \
  } while (0)

#define LOAD_A(aF, lbuf, h) do {                                              \
    const __hip_bfloat16* _b = (lbuf) + (wr * 128 + (h) * 64 + lr) * 64;      \
    _Pragma("unroll")                                                         \
    for (int _i = 0; _i < 4; _i++) {                                          \
      aF[_i][0] = *(const bf16x8*)&_b[_i * 1024 + pc0];                       \
      aF[_i][1] = *(const bf16x8*)&_b[_i * 1024 + pc1];                       \
    }                                                                         \
  } while (0)
#define LOAD_B(bF, lbuf, g) do {                                              \
    const __hip_bfloat16* _b = (lbuf) + (wc * 64 + (g) * 32 + lr) * 64;       \
    _Pragma("unroll")                                                         \
    for (int _j = 0; _j < 2; _j++) {                                          \
      bF[_j][0] = *(const bf16x8*)&_b[_j * 1024 + pc0];                       \
      bF[_j][1] = *(const bf16x8*)&_b[_j * 1024 + pc1];                       \
    }                                                                         \
  } while (0)
#define LOAD_B1(bF, lbuf, g) do {                                             \
    const __hip_bfloat16* _b = (lbuf) + (wc * 32 + (g) * 16 + lr) * 64;       \
    bF[0] = *(const bf16x8*)&_b[pc0];                                         \
    bF[1] = *(const bf16x8*)&_b[pc1];                                         \
  } while (0)

#define MFMA_Q(aF, bF, h, g) do {                                             \
    __builtin_amdgcn_s_setprio(1);                                            \
    _Pragma("unroll")                                                         \
    for (int _i = 0; _i < 4; _i++)                                            \
      _Pragma("unroll")                                                       \
      for (int _j = 0; _j < 2; _j++) {                                        \
        acc[(h) * 4 + _i][(g) * 2 + _j] =                                     \
          __builtin_amdgcn_mfma_f32_16x16x32_bf16(aF[_i][0], bF[_j][0],       \
              acc[(h) * 4 + _i][(g) * 2 + _j], 0, 0, 0);                      \
        acc[(h) * 4 + _i][(g) * 2 + _j] =                                     \
          __builtin_amdgcn_mfma_f32_16x16x32_bf16(aF[_i][1], bF[_j][1],       \
              acc[(h) * 4 + _i][(g) * 2 + _j], 0, 0, 0);                      \
      }                                                                       \
    __builtin_amdgcn_s_setprio(0);                                            \
  } while (0)
#define MFMA_Q1(aF, bF, h, g) do {                                            \
    __builtin_amdgcn_s_setprio(1);                                            \
    _Pragma("unroll")                                                         \
    for (int _i = 0; _i < 4; _i++) {                                          \
      acc[(h) * 4 + _i][(g)] =                                                \
        __builtin_amdgcn_mfma_f32_16x16x32_bf16(aF[_i][0], bF[0],             \
            acc[(h) * 4 + _i][(g)], 0, 0, 0);                                 \
      acc[(h) * 4 + _i][(g)] =                                                \
        __builtin_amdgcn_mfma_f32_16x16x32_bf16(aF[_i][1], bF[1],             \
            acc[(h) * 4 + _i][(g)], 0, 0, 0);                                 \
    }                                                                         \
    __builtin_amdgcn_s_setprio(0);                                            \
  } while (0)

#define ZERO_ACC(acc)                         \
  {                                           \
    f32x4 _z = {0.f, 0.f, 0.f, 0.f};          \
    _Pragma("unroll")                         \
    for (int _i = 0; _i < 8; _i++)            \
      _Pragma("unroll")                       \
      for (int _j = 0; _j < 4; _j++)          \
        acc[_i][_j] = _z;                     \
  }
#define ZERO_ACC2(acc)                        \
  {                                           \
    f32x4 _z = {0.f, 0.f, 0.f, 0.f};          \
    _Pragma("unroll")                         \
    for (int _i = 0; _i < 8; _i++)            \
      _Pragma("unroll")                       \
      for (int _j = 0; _j < 2; _j++)          \
        acc[_i][_j] = _z;                     \
  }

static __device__ __forceinline__ void gemm256(
    const __hip_bfloat16* __restrict__ A, int lda,
    const __hip_bfloat16* __restrict__ Bt, int ldb,
    int K, f32x4 (&acc)[8][4])
{
  __shared__ __hip_bfloat16 sA[2][128 * 64 * 2];   // 64 KiB
  __shared__ __hip_bfloat16 sB[2][128 * 64 * 2];   // 64 KiB

  const int t    = threadIdx.x;   // 0..511
  const int wave = t >> 6;
  const int lane = t & 63;
  const int quad = lane >> 4;
  const int lr   = lane & 15;
  const int wr   = wave >> 2;     // 0..1  (M)
  const int wc   = wave & 3;      // 0..3  (N)

  const int r0 = t >> 3;
  const int cs = (((t & 7) ^ (r0 & 7)) << 3);
  const __hip_bfloat16* gA = A  + (size_t)r0 * lda + cs;
  const __hip_bfloat16* gB = Bt + (size_t)r0 * ldb + cs;

  const int pc0 = ((quad)     ^ (lr & 7)) << 3;
  const int pc1 = ((quad + 4) ^ (lr & 7)) << 3;

  const __hip_bfloat16* const lA0 = sA[0];
  const __hip_bfloat16* const lA1 = sA[1];
  const __hip_bfloat16* const lB0 = sB[0];
  const __hip_bfloat16* const lB1 = sB[1];

  const int nt    = K >> 6;
  const int niter = nt >> 1;

  STAGE_A(0, 0, 0);
  STAGE_A(0, 1, 0);
  STAGE_B(0, 0, 0);
  STAGE_B(0, 1, 0);
  STAGE_A(1, 0, 1);
  STAGE_B(1, 1, 1);
  VMCNT4;
  BAR;

  bf16x8 aF[4][2], bFa[2][2], bFb[2][2];

  for (int j = 0; j < niter - 1; ++j) {
    const int tb = 2 * j + 1, tc = tb + 1, td = tb + 2;

    LOAD_A(aF, lA0, 0); LOAD_B(bFa, lB0, 0);
    STAGE_B(1, 0, tb);
    BAR; MFMA_Q(aF, bFa, 0, 0); BAR;

    LOAD_B(bFb, lB0, 1);
    STAGE_A(1, 1, tb);
    BAR; MFMA_Q(aF, bFb, 0, 1); BAR;

    LOAD_A(aF, lA0, 1);
    STAGE_A(0, 0, tc);
    BAR; MFMA_Q(aF, bFb, 1, 1); BAR;

    STAGE_B(0, 1, tc);
    VMCNT4;
    BAR; MFMA_Q(aF, bFa, 1, 0); BAR;

    LOAD_A(aF, lA1, 0); LOAD_B(bFa, lB1, 0);
    STAGE_B(0, 0, tc);
    BAR; MFMA_Q(aF, bFa, 0, 0); BAR;

    LOAD_B(bFb, lB1, 1);
    STAGE_A(0, 1, tc);
    BAR; MFMA_Q(aF, bFb, 0, 1); BAR;

    LOAD_A(aF, lA1, 1);
    STAGE_A(1, 0, td);
    BAR; MFMA_Q(aF, bFb, 1, 1); BAR;

    STAGE_B(1, 1, td);
    VMCNT4;
    BAR; MFMA_Q(aF, bFa, 1, 0); BAR;
  }

  {
    const int tb = nt - 1;
    LOAD_A(aF, lA0, 0); LOAD_B(bFa, lB0, 0);
    STAGE_B(1, 0, tb);
    BAR; MFMA_Q(aF, bFa, 0, 0); BAR;

    LOAD_B(bFb, lB0, 1);
    STAGE_A(1, 1, tb);
    BAR; MFMA_Q(aF, bFb, 0, 1); BAR;

    LOAD_A(aF, lA0, 1);
    BAR; MFMA_Q(aF, bFb, 1, 1); BAR;

    VMCNT0;
    BAR; MFMA_Q(aF, bFa, 1, 0); BAR;

    LOAD_A(aF, lA1, 0); LOAD_B(bFa, lB1, 0);
    BAR; MFMA_Q(aF, bFa, 0, 0); BAR;

    LOAD_B(bFb, lB1, 1);
    BAR; MFMA_Q(aF, bFb, 0, 1); BAR;

    LOAD_A(aF, lA1, 1);
    BAR; MFMA_Q(aF, bFb, 1, 1); BAR;

    MFMA_Q(aF, bFa, 1, 0);
  }
}

// 256x128 tile, identical phase/ledger structure; B-half = 1 copy -> vmcnt(3).
static __device__ __forceinline__ void gemm256x128(
    const __hip_bfloat16* __restrict__ A, int lda,
    const __hip_bfloat16* __restrict__ Bt, int ldb,
    int K, f32x4 (&acc)[8][2])
{
  __shared__ __hip_bfloat16 sA[2][128 * 64 * 2];   // 64 KiB
  __shared__ __hip_bfloat16 sB[2][64 * 64 * 2];    // 32 KiB

  const int t    = threadIdx.x;
  const int wave = t >> 6;
  const int lane = t & 63;
  const int quad = lane >> 4;
  const int lr   = lane & 15;
  const int wr   = wave >> 2;     // 0..1  (M)
  const int wc   = wave & 3;      // 0..3  (N, 32 cols each)

  const int r0 = t >> 3;
  const int cs = (((t & 7) ^ (r0 & 7)) << 3);
  const __hip_bfloat16* gA = A  + (size_t)r0 * lda + cs;
  const __hip_bfloat16* gB = Bt + (size_t)r0 * ldb + cs;

  const int pc0 = ((quad)     ^ (lr & 7)) << 3;
  const int pc1 = ((quad + 4) ^ (lr & 7)) << 3;

  const __hip_bfloat16* const lA0 = sA[0];
  const __hip_bfloat16* const lA1 = sA[1];
  const __hip_bfloat16* const lB0 = sB[0];
  const __hip_bfloat16* const lB1 = sB[1];

  const int nt    = K >> 6;
  const int niter = nt >> 1;

  // prologue: tile0 complete (6 copies) + A-lo(1) (2), B-hi(1) (1) in flight.
  STAGE_A(0, 0, 0);
  STAGE_A(0, 1, 0);
  STAGE_B1(0, 0, 0);
  STAGE_B1(0, 1, 0);
  STAGE_A(1, 0, 1);
  STAGE_B1(1, 1, 1);
  VMCNT3;
  BAR;

  bf16x8 aF[4][2], bFa[2], bFb[2];

  for (int j = 0; j < niter - 1; ++j) {
    const int tb = 2 * j + 1, tc = tb + 1, td = tb + 2;

    LOAD_A(aF, lA0, 0); LOAD_B1(bFa, lB0, 0);
    STAGE_B1(1, 0, tb);
    BAR; MFMA_Q1(aF, bFa, 0, 0); BAR;

    LOAD_B1(bFb, lB0, 1);
    STAGE_A(1, 1, tb);
    BAR; MFMA_Q1(aF, bFb, 0, 1); BAR;

    LOAD_A(aF, lA0, 1);
    STAGE_A(0, 0, tc);
    BAR; MFMA_Q1(aF, bFb, 1, 1); BAR;

    STAGE_B1(0, 1, tc);
    VMCNT3;                    // tile tb's 6 copies complete; 3 newest remain
    BAR; MFMA_Q1(aF, bFa, 1, 0); BAR;

    LOAD_A(aF, lA1, 0); LOAD_B1(bFa, lB1, 0);
    STAGE_B1(0, 0, tc);
    BAR; MFMA_Q1(aF, bFa, 0, 0); BAR;

    LOAD_B1(bFb, lB1, 1);
    STAGE_A(0, 1, tc);
    BAR; MFMA_Q1(aF, bFb, 0, 1); BAR;

    LOAD_A(aF, lA1, 1);
    STAGE_A(1, 0, td);
    BAR; MFMA_Q1(aF, bFb, 1, 1); BAR;

    STAGE_B1(1, 1, td);
    VMCNT3;
    BAR; MFMA_Q1(aF, bFa, 1, 0); BAR;
  }

  {
    const int tb = nt - 1;
    LOAD_A(aF, lA0, 0); LOAD_B1(bFa, lB0, 0);
    STAGE_B1(1, 0, tb);
    BAR; MFMA_Q1(aF, bFa, 0, 0); BAR;

    LOAD_B1(bFb, lB0, 1);
    STAGE_A(1, 1, tb);
    BAR; MFMA_Q1(aF, bFb, 0, 1); BAR;

    LOAD_A(aF, lA0, 1);
    BAR; MFMA_Q1(aF, bFb, 1, 1); BAR;

    VMCNT0;
    BAR; MFMA_Q1(aF, bFa, 1, 0); BAR;

    LOAD_A(aF, lA1, 0); LOAD_B1(bFa, lB1, 0);
    BAR; MFMA_Q1(aF, bFa, 0, 0); BAR;

    LOAD_B1(bFb, lB1, 1);
    BAR; MFMA_Q1(aF, bFb, 0, 1); BAR;

    LOAD_A(aF, lA1, 1);
    BAR; MFMA_Q1(aF, bFb, 1, 1); BAR;

    MFMA_Q1(aF, bFa, 1, 0);
  }
}

// ---------------- fused prep: z<3 -> transpose+cast W; z==3 -> cast x ----------------
__global__ __launch_bounds__(256) void prep_kernel(
    const float* __restrict__ x,
    const float* __restrict__ Wq,
    const float* __restrict__ Wk,
    const float* __restrict__ Wv,
    __hip_bfloat16* __restrict__ xb,
    __hip_bfloat16* __restrict__ Wt3)
{
  const int tx = threadIdx.x, ty = threadIdx.y;  // (32,8)
  if (blockIdx.z == 3) {
    const int tid = ty * 32 + tx;
    const size_t base = ((size_t)blockIdx.y * 32 + blockIdx.x) * 8192;
#pragma unroll
    for (int p = 0; p < 8; p++) {
      const size_t i = base + p * 1024 + tid * 4;
      const float4 v = *(const float4*)(x + i);
      __hip_bfloat16 o[4] = {__float2bfloat16(v.x), __float2bfloat16(v.y),
                             __float2bfloat16(v.z), __float2bfloat16(v.w)};
      *(uint64_t*)(xb + i) = *(uint64_t*)o;
    }
    return;
  }
  const float* src = (blockIdx.z == 0) ? Wq : (blockIdx.z == 1) ? Wk : Wv;
  __hip_bfloat16* dst = Wt3 + (size_t)blockIdx.z * D_EMB * D_EMB;
  __shared__ __hip_bfloat16 tile[32][33];
  const int x0 = blockIdx.x * 32;  // e
  const int y0 = blockIdx.y * 32;  // d
#pragma unroll
  for (int i = 0; i < 32; i += 8)
    tile[ty + i][tx] = __float2bfloat16(src[(size_t)(y0 + ty + i) * D_EMB + (x0 + tx)]);
  __syncthreads();
#pragma unroll
  for (int i = 0; i < 32; i += 8)
    dst[(size_t)(x0 + ty + i) * D_EMB + (y0 + tx)] = tile[tx][ty + i];
}

// ---------------- QKV projections (R1-verbatim: per-tile 256^2, 8-phase) ----------------
// grid (32 m-tiles, 4 n-tiles, 3 mats), m fastest.
// z=0: Q[b][s][e], z=1: K[b][s][e], z=2: V transposed -> Vt[b][e][s]
__global__ __launch_bounds__(512, 2) void qkv_kernel(
    const __hip_bfloat16* __restrict__ xb,
    const __hip_bfloat16* __restrict__ Wt3,
    const float* __restrict__ bq,
    const float* __restrict__ bk,
    const float* __restrict__ bv,
    __hip_bfloat16* __restrict__ Q,
    __hip_bfloat16* __restrict__ Kb,
    __hip_bfloat16* __restrict__ Vt)
{
  const int mat = blockIdx.z;
  const int m0  = blockIdx.x * 256;
  const int n0  = blockIdx.y * 256;

  f32x4 acc[8][4];
  ZERO_ACC(acc);

  gemm256(xb + (size_t)m0 * D_EMB, D_EMB,
          Wt3 + (size_t)mat * D_EMB * D_EMB + (size_t)n0 * D_EMB, D_EMB,
          D_EMB, acc);

  const float* bias = (mat == 0) ? bq : (mat == 1) ? bk : bv;

  const int t = threadIdx.x;
  const int wave = t >> 6, lane = t & 63;
  const int quad = lane >> 4, lr = lane & 15;
  const int wr = wave >> 2, wc = wave & 3;

#pragma unroll
  for (int i = 0; i < 8; i++) {
#pragma unroll
    for (int j = 0; j < 4; j++) {
      const int n = n0 + wc * 64 + j * 16 + lr;
      const float bb = bias[n];
      const int mbase = m0 + wr * 128 + i * 16 + quad * 4;
      if (mat == 2) {
        const int b = mbase >> 11, s = mbase & 2047;
        __hip_bfloat16 pk[4];
#pragma unroll
        for (int r = 0; r < 4; r++) pk[r] = __float2bfloat16(acc[i][j][r] + bb);
        *(uint64_t*)&Vt[(size_t)b * D_EMB * SEQ + (size_t)n * SEQ + s] = *(uint64_t*)pk;
      } else {
        __hip_bfloat16* dst = (mat == 0) ? Q : Kb;
#pragma unroll
        for (int r = 0; r < 4; r++)
          dst[(size_t)(mbase + r) * D_EMB + n] = __float2bfloat16(acc[i][j][r] + bb);
      }
    }
  }
}

// ---------------- scores = Q @ K^T * scale (fp16 out) ----------------
__global__ __launch_bounds__(512, 2) void scores_kernel(
    const __hip_bfloat16* __restrict__ Q,
    const __hip_bfloat16* __restrict__ Kb,
    __half* __restrict__ Sc)
{
  const int b  = blockIdx.z;
  const int m0 = blockIdx.y * 256;  // s_q
  const int n0 = blockIdx.x * 256;  // s_k

  f32x4 acc[8][4];
  ZERO_ACC(acc);

  gemm256(Q  + (size_t)b * SEQ * D_EMB + (size_t)m0 * D_EMB, D_EMB,
          Kb + (size_t)b * SEQ * D_EMB + (size_t)n0 * D_EMB, D_EMB,
          D_EMB, acc);

  __half* out = Sc + (size_t)b * SEQ * SEQ;
  const float scale = 0.03125f;  // 1/sqrt(1024)

  const int t = threadIdx.x;
  const int wave = t >> 6, lane = t & 63;
  const int quad = lane >> 4, lr = lane & 15;
  const int wr = wave >> 2, wc = wave & 3;

#pragma unroll
  for (int i = 0; i < 8; i++)
#pragma unroll
    for (int j = 0; j < 4; j++) {
      const int n = n0 + wc * 64 + j * 16 + lr;
#pragma unroll
      for (int r = 0; r < 4; r++) {
        const int m = m0 + wr * 128 + i * 16 + quad * 4 + r;
        out[(size_t)m * SEQ + n] = __float2half(acc[i][j][r] * scale);
      }
    }
}

// ---------------- row softmax: fp16 scores -> bf16 probs (16B vectorized) ----------------
__global__ __launch_bounds__(256) void softmax_kernel(
    const __half* __restrict__ Sc, __hip_bfloat16* __restrict__ P)
{
  const int row = blockIdx.x;  // 0..8191
  const __half* src = Sc + (size_t)row * SEQ;
  const int t = threadIdx.x;
  const int wave = t >> 6, lane = t & 63;

  const short8 raw = *(const short8*)(src + t * 8);
  float v[8];
#pragma unroll
  for (int i = 0; i < 8; i++) {
    const short si = raw[i];
    __half h;
    memcpy(&h, &si, sizeof(h));
    v[i] = __half2float(h);
  }

  float m = v[0];
#pragma unroll
  for (int i = 1; i < 8; i++) m = fmaxf(m, v[i]);
#pragma unroll
  for (int o = 32; o > 0; o >>= 1) m = fmaxf(m, __shfl_xor(m, o));

  __shared__ float redm[4];
  __shared__ float reds[4];
  if (lane == 0) redm[wave] = m;
  __syncthreads();
  m = fmaxf(fmaxf(redm[0], redm[1]), fmaxf(redm[2], redm[3]));

  float e[8], s = 0.f;
#pragma unroll
  for (int i = 0; i < 8; i++) { e[i] = __expf(v[i] - m); s += e[i]; }
#pragma unroll
  for (int o = 32; o > 0; o >>= 1) s += __shfl_xor(s, o);
  if (lane == 0) reds[wave] = s;
  __syncthreads();
  s = reds[0] + reds[1] + reds[2] + reds[3];

  const float inv = 1.f / s;
  short8 outp;
#pragma unroll
  for (int i = 0; i < 8; i++) {
    const __hip_bfloat16 b = __float2bfloat16(e[i] * inv);
    short sb;
    memcpy(&sb, &b, sizeof(sb));
    outp[i] = sb;
  }
  *(short8*)(P + (size_t)row * SEQ + t * 8) = outp;
}

// ---------------- out(fp32) = P @ V  (256x128 tiles -> 256 blocks, 1 round) ----------------
__global__ __launch_bounds__(512, 2) void pv_kernel(
    const __hip_bfloat16* __restrict__ P,
    const __hip_bfloat16* __restrict__ Vt,
    float* __restrict__ out)
{
  const int b  = blockIdx.z;
  const int m0 = blockIdx.y * 256;  // s_q
  const int n0 = blockIdx.x * 128;  // e

  f32x4 acc[8][2];
  ZERO_ACC2(acc);

  gemm256x128(P  + (size_t)b * SEQ * SEQ   + (size_t)m0 * SEQ, SEQ,
              Vt + (size_t)b * D_EMB * SEQ + (size_t)n0 * SEQ, SEQ,
              SEQ, acc);

  float* o = out + (size_t)b * SEQ * D_EMB;

  const int t = threadIdx.x;
  const int wave = t >> 6, lane = t & 63;
  const int quad = lane >> 4, lr = lane & 15;
  const int wr = wave >> 2, wc = wave & 3;

#pragma unroll
  for (int i = 0; i < 8; i++)
#pragma unroll
    for (int j = 0; j < 2; j++) {
      const int n = n0 + wc * 32 + j * 16 + lr;
#pragma unroll
      for (int r = 0; r < 4; r++) {
        const int m = m0 + wr * 128 + i * 16 + quad * 4 + r;
        o[(size_t)m * D_EMB + n] = acc[i][j][r];
      }
    }
}

extern "C" void kernel_launch(void* const* d_in, const int* in_sizes, int n_in,
                              void* d_out, int out_size, void* d_ws, size_t ws_size,
                              hipStream_t stream) {
  const float* x  = (const float*)d_in[0];
  const float* Wq = (const float*)d_in[1];
  const float* bq = (const float*)d_in[2];
  const float* Wk = (const float*)d_in[3];
  const float* bk = (const float*)d_in[4];
  const float* Wv = (const float*)d_in[5];
  const float* bv = (const float*)d_in[6];
  float* out = (float*)d_out;

  char* ws = (char*)d_ws;
  __hip_bfloat16* xb  = (__hip_bfloat16*)(ws);
  __hip_bfloat16* Wt3 = (__hip_bfloat16*)(ws + 16777216);
  __hip_bfloat16* Q   = (__hip_bfloat16*)(ws + 23068672);
  __hip_bfloat16* Kb  = (__hip_bfloat16*)(ws + 39845888);
  __hip_bfloat16* Vt  = (__hip_bfloat16*)(ws + 56623104);
  __half*         Sc  = (__half*)        (ws + 73400320);   // 32 MB fp16
  __hip_bfloat16* P   = (__hip_bfloat16*)(ws + 140509184);
  // total = 140509184 + 33554432 = 174,063,616 bytes (~166 MB)

  prep_kernel  <<<dim3(32, 32, 4), dim3(32, 8), 0, stream>>>(x, Wq, Wk, Wv, xb, Wt3);
  qkv_kernel   <<<dim3(32, 4, 3),  512,        0, stream>>>(xb, Wt3, bq, bk, bv, Q, Kb, Vt);
  scores_kernel<<<dim3(8, 8, 4),   512,        0, stream>>>(Q, Kb, Sc);
  softmax_kernel<<<dim3(8192),     256,        0, stream>>>(Sc, P);
  pv_kernel    <<<dim3(8, 8, 4),   512,        0, stream>>>(P, Vt, out);
}

// Round 4
// 267.233 us; speedup vs baseline: 1.1347x; 1.0001x over previous
//
#include <hip/hip_runtime.h>
#include <hip/hip_bf16.h>
#include <hip/hip_fp16.h>
#include <stdint.h>
#include <stddef.h>
#include <string.h>

#define D_EMB 1024
#define SEQ   2048
#define BATCH 4

typedef short bf16x8  __attribute__((ext_vector_type(8)));
typedef short short8  __attribute__((ext_vector_type(8)));
typedef float f32x4   __attribute__((ext_vector_type(4)));

#define AS1 __attribute__((address_space(1)))
#define AS3 __attribute__((address_space(3)))

static __device__ __forceinline__ void async_copy16(const void* g, void* l) {
  __builtin_amdgcn_global_load_lds((const AS1 void*)g, (AS3 void*)l, 16, 0, 0);
}

// ============================================================================
// 8-phase 256-wide GEMM cores — R4: RE-DERIVED STAGING LEDGER.
// R3 audit found two defects in the R1 ledger:
//  (a) p3 staged into buf0-A rows 0-127 while p3's own LOAD_A(lA0,1) was
//      reading rows 64-127 (same phase) — latent write-under-read race that
//      only passed because copy-return latency > intra-phase skew;
//  (b) newest halves were issued at p1/p2 and drained at p4 — ~2 phases
//      (~400cy) of latency cover vs 200-900cy memory latency, stalling the
//      whole CU (1 block/CU) at every vmcnt.
// New ledger (stage strictly AFTER the slot's last read, >=2 barriers):
//   reads: buf0-B free@p2, buf0-A free@p3, buf1-B free@p6, buf1-A free@p7
//   stages: p1: A(1,hi,tb) | p3: B(0,lo,tc) | p4: B(0,hi,tc)+A(0,lo,tc)
//           p5: A(0,hi,tc) | p7: B(1,lo,td) | p8: B(1,hi,td)+A(1,lo,td)
//   drains: p4/p8 vmcnt leaves the 6 newest copies in flight (x128: 4),
//           draining exactly the 8 (x128: 6) copies of the buffer consumed
//           in the next phase. Cover depth now 3-6 phases.
// Invariant entering p1: buf0 complete; buf1 missing only A-hi (issued p1).
// R2 LESSON stands: no mid-loop accumulator stores (79 MB scratch spill).
// ============================================================================

#define BAR     __builtin_amdgcn_s_barrier()
#define VMCNT6  asm volatile("s_waitcnt vmcnt(6)" ::: "memory")
#define VMCNT4  asm volatile("s_waitcnt vmcnt(4)" ::: "memory")
#define VMCNT0  asm volatile("s_waitcnt vmcnt(0)" ::: "memory")

#define STAGE_A(buf, h, kt) do {                                              \
    const __hip_bfloat16* _g = gA + (size_t)((h) * 128) * lda + ((kt) << 6);  \
    char* _l = (char*)sA + (buf) * 32768 + (h) * 16384 + wave * 1024;         \
    async_copy16(_g, _l);                                                     \
    async_copy16(_g + (size_t)64 * lda, _l + 8192);                           \
  } while (0)
#define STAGE_B(buf, h, kt) do {                                              \
    const __hip_bfloat16* _g = gB + (size_t)((h) * 128) * ldb + ((kt) << 6);  \
    char* _l = (char*)sB + (buf) * 32768 + (h) * 16384 + wave * 1024;         \
    async_copy16(_g, _l);                                                     \
    async_copy16(_g + (size_t)64 * ldb, _l + 8192);                           \
  } while (0)
// B-half for the x128 variant: 64 rows = exactly 512 threads * 16B = 1 copy.
#define STAGE_B1(buf, h, kt) do {                                             \
    const __hip_bfloat16* _g = gB + (size_t)((h) * 64) * ldb + ((kt) << 6);   \
    char* _l = (char*)sB + (buf) * 16384 + (h) * 8192 + wave * 1024;          \
    async_copy16(_g, _l);                                                     \
  } while (0)

#define LOAD_A(aF, lbuf, h) do {                                              \
    const __hip_bfloat16* _b = (lbuf) + (wr * 128 + (h) * 64 + lr) * 64;      \
    _Pragma("unroll")                                                         \
    for (int _i = 0; _i < 4; _i++) {                                          \
      aF[_i][0] = *(const bf16x8*)&_b[_i * 1024 + pc0];                       \
      aF[_i][1] = *(const bf16x8*)&_b[_i * 1024 + pc1];                       \
    }                                                                         \
  } while (0)
#define LOAD_B(bF, lbuf, g) do {                                              \
    const __hip_bfloat16* _b = (lbuf) + (wc * 64 + (g) * 32 + lr) * 64;       \
    _Pragma("unroll")                                                         \
    for (int _j = 0; _j < 2; _j++) {                                          \
      bF[_j][0] = *(const bf16x8*)&_b[_j * 1024 + pc0];                       \
      bF[_j][1] = *(const bf16x8*)&_b[_j * 1024 + pc1];                       \
    }                                                                         \
  } while (0)
#define LOAD_B1(bF, lbuf, g) do {                                             \
    const __hip_bfloat16* _b = (lbuf) + (wc * 32 + (g) * 16 + lr) * 64;       \
    bF[0] = *(const bf16x8*)&_b[pc0];                                         \
    bF[1] = *(const bf16x8*)&_b[pc1];                                         \
  } while (0)

#define MFMA_Q(aF, bF, h, g) do {                                             \
    __builtin_amdgcn_s_setprio(1);                                            \
    _Pragma("unroll")                                                         \
    for (int _i = 0; _i < 4; _i++)                                            \
      _Pragma("unroll")                                                       \
      for (int _j = 0; _j < 2; _j++) {                                        \
        acc[(h) * 4 + _i][(g) * 2 + _j] =                                     \
          __builtin_amdgcn_mfma_f32_16x16x32_bf16(aF[_i][0], bF[_j][0],       \
              acc[(h) * 4 + _i][(g) * 2 + _j], 0, 0, 0);                      \
        acc[(h) * 4 + _i][(g) * 2 + _j] =                                     \
          __builtin_amdgcn_mfma_f32_16x16x32_bf16(aF[_i][1], bF[_j][1],       \
              acc[(h) * 4 + _i][(g) * 2 + _j], 0, 0, 0);                      \
      }                                                                       \
    __builtin_amdgcn_s_setprio(0);                                            \
  } while (0)
#define MFMA_Q1(aF, bF, h, g) do {                                            \
    __builtin_amdgcn_s_setprio(1);                                            \
    _Pragma("unroll")                                                         \
    for (int _i = 0; _i < 4; _i++) {                                          \
      acc[(h) * 4 + _i][(g)] =                                                \
        __builtin_amdgcn_mfma_f32_16x16x32_bf16(aF[_i][0], bF[0],             \
            acc[(h) * 4 + _i][(g)], 0, 0, 0);                                 \
      acc[(h) * 4 + _i][(g)] =                                                \
        __builtin_amdgcn_mfma_f32_16x16x32_bf16(aF[_i][1], bF[1],             \
            acc[(h) * 4 + _i][(g)], 0, 0, 0);                                 \
    }                                                                         \
    __builtin_amdgcn_s_setprio(0);                                            \
  } while (0)

#define ZERO_ACC(acc)                         \
  {                                           \
    f32x4 _z = {0.f, 0.f, 0.f, 0.f};          \
    _Pragma("unroll")                         \
    for (int _i = 0; _i < 8; _i++)            \
      _Pragma("unroll")                       \
      for (int _j = 0; _j < 4; _j++)          \
        acc[_i][_j] = _z;                     \
  }
#define ZERO_ACC2(acc)                        \
  {                                           \
    f32x4 _z = {0.f, 0.f, 0.f, 0.f};          \
    _Pragma("unroll")                         \
    for (int _i = 0; _i < 8; _i++)            \
      _Pragma("unroll")                       \
      for (int _j = 0; _j < 2; _j++)          \
        acc[_i][_j] = _z;                     \
  }

static __device__ __forceinline__ void gemm256(
    const __hip_bfloat16* __restrict__ A, int lda,
    const __hip_bfloat16* __restrict__ Bt, int ldb,
    int K, f32x4 (&acc)[8][4])
{
  __shared__ __hip_bfloat16 sA[2][128 * 64 * 2];   // 64 KiB
  __shared__ __hip_bfloat16 sB[2][128 * 64 * 2];   // 64 KiB

  const int t    = threadIdx.x;   // 0..511
  const int wave = t >> 6;
  const int lane = t & 63;
  const int quad = lane >> 4;
  const int lr   = lane & 15;
  const int wr   = wave >> 2;     // 0..1  (M)
  const int wc   = wave & 3;      // 0..3  (N)

  const int r0 = t >> 3;
  const int cs = (((t & 7) ^ (r0 & 7)) << 3);
  const __hip_bfloat16* gA = A  + (size_t)r0 * lda + cs;
  const __hip_bfloat16* gB = Bt + (size_t)r0 * ldb + cs;

  const int pc0 = ((quad)     ^ (lr & 7)) << 3;
  const int pc1 = ((quad + 4) ^ (lr & 7)) << 3;

  const __hip_bfloat16* const lA0 = sA[0];
  const __hip_bfloat16* const lA1 = sA[1];
  const __hip_bfloat16* const lB0 = sB[0];
  const __hip_bfloat16* const lB1 = sB[1];

  const int nt    = K >> 6;
  const int niter = nt >> 1;

  // prologue: T0 complete (8 copies) + T1 B-lo,B-hi,A-lo (6 in flight).
  STAGE_A(0, 0, 0);
  STAGE_A(0, 1, 0);
  STAGE_B(0, 0, 0);
  STAGE_B(0, 1, 0);
  STAGE_B(1, 0, 1);
  STAGE_B(1, 1, 1);
  STAGE_A(1, 0, 1);
  VMCNT6;                 // drains T0's 8; T1's 6 stay in flight
  BAR;

  bf16x8 aF[4][2], bFa[2][2], bFb[2][2];

  for (int j = 0; j < niter - 1; ++j) {
    const int tb = 2 * j + 1, tc = tb + 1, td = tb + 2;

    // p1 (buf0, h0,g0) — complete buf1 by issuing its A-hi
    LOAD_A(aF, lA0, 0); LOAD_B(bFa, lB0, 0);
    STAGE_A(1, 1, tb);
    BAR; MFMA_Q(aF, bFa, 0, 0); BAR;

    // p2 (h0,g1)
    LOAD_B(bFb, lB0, 1);
    BAR; MFMA_Q(aF, bFb, 0, 1); BAR;

    // p3 (h1,g1) — buf0-B free after p2
    LOAD_A(aF, lA0, 1);
    STAGE_B(0, 0, tc);
    BAR; MFMA_Q(aF, bFb, 1, 1); BAR;

    // p4 (h1,g0) — buf0-A free after p3; drain buf1 (8 oldest of 14)
    STAGE_B(0, 1, tc);
    STAGE_A(0, 0, tc);
    VMCNT6;
    BAR; MFMA_Q(aF, bFa, 1, 0); BAR;

    // p5 (buf1, h0,g0)
    LOAD_A(aF, lA1, 0); LOAD_B(bFa, lB1, 0);
    STAGE_A(0, 1, tc);
    BAR; MFMA_Q(aF, bFa, 0, 0); BAR;

    // p6 (h0,g1)
    LOAD_B(bFb, lB1, 1);
    BAR; MFMA_Q(aF, bFb, 0, 1); BAR;

    // p7 (h1,g1) — buf1-B free after p6
    LOAD_A(aF, lA1, 1);
    STAGE_B(1, 0, td);
    BAR; MFMA_Q(aF, bFb, 1, 1); BAR;

    // p8 (h1,g0) — buf1-A free after p7; drain buf0 (8 oldest of 14)
    STAGE_B(1, 1, td);
    STAGE_A(1, 0, td);
    VMCNT6;
    BAR; MFMA_Q(aF, bFa, 1, 0); BAR;
  }

  { // final pair: tiles nt-2 (buf0), nt-1 (buf1); buf1 missing only A-hi.
    const int tb = nt - 1;
    LOAD_A(aF, lA0, 0); LOAD_B(bFa, lB0, 0);
    STAGE_A(1, 1, tb);
    BAR; MFMA_Q(aF, bFa, 0, 0); BAR;

    LOAD_B(bFb, lB0, 1);
    BAR; MFMA_Q(aF, bFb, 0, 1); BAR;

    LOAD_A(aF, lA0, 1);
    BAR; MFMA_Q(aF, bFb, 1, 1); BAR;

    VMCNT0;                       // buf1's 8 copies complete
    BAR; MFMA_Q(aF, bFa, 1, 0); BAR;

    LOAD_A(aF, lA1, 0); LOAD_B(bFa, lB1, 0);
    BAR; MFMA_Q(aF, bFa, 0, 0); BAR;

    LOAD_B(bFb, lB1, 1);
    BAR; MFMA_Q(aF, bFb, 0, 1); BAR;

    LOAD_A(aF, lA1, 1);
    BAR; MFMA_Q(aF, bFb, 1, 1); BAR;

    MFMA_Q(aF, bFa, 1, 0);
  }
}

// 256x128 tile, same re-derived ledger; B copies are 1 each -> vmcnt(4).
static __device__ __forceinline__ void gemm256x128(
    const __hip_bfloat16* __restrict__ A, int lda,
    const __hip_bfloat16* __restrict__ Bt, int ldb,
    int K, f32x4 (&acc)[8][2])
{
  __shared__ __hip_bfloat16 sA[2][128 * 64 * 2];   // 64 KiB
  __shared__ __hip_bfloat16 sB[2][64 * 64 * 2];    // 32 KiB

  const int t    = threadIdx.x;
  const int wave = t >> 6;
  const int lane = t & 63;
  const int quad = lane >> 4;
  const int lr   = lane & 15;
  const int wr   = wave >> 2;     // 0..1  (M)
  const int wc   = wave & 3;      // 0..3  (N, 32 cols each)

  const int r0 = t >> 3;
  const int cs = (((t & 7) ^ (r0 & 7)) << 3);
  const __hip_bfloat16* gA = A  + (size_t)r0 * lda + cs;
  const __hip_bfloat16* gB = Bt + (size_t)r0 * ldb + cs;

  const int pc0 = ((quad)     ^ (lr & 7)) << 3;
  const int pc1 = ((quad + 4) ^ (lr & 7)) << 3;

  const __hip_bfloat16* const lA0 = sA[0];
  const __hip_bfloat16* const lA1 = sA[1];
  const __hip_bfloat16* const lB0 = sB[0];
  const __hip_bfloat16* const lB1 = sB[1];

  const int nt    = K >> 6;
  const int niter = nt >> 1;

  // prologue: T0 complete (6 copies) + T1 B-lo,B-hi,A-lo (4 in flight).
  STAGE_A(0, 0, 0);
  STAGE_A(0, 1, 0);
  STAGE_B1(0, 0, 0);
  STAGE_B1(0, 1, 0);
  STAGE_B1(1, 0, 1);
  STAGE_B1(1, 1, 1);
  STAGE_A(1, 0, 1);
  VMCNT4;                 // drains T0's 6; T1's 4 stay in flight
  BAR;

  bf16x8 aF[4][2], bFa[2], bFb[2];

  for (int j = 0; j < niter - 1; ++j) {
    const int tb = 2 * j + 1, tc = tb + 1, td = tb + 2;

    LOAD_A(aF, lA0, 0); LOAD_B1(bFa, lB0, 0);
    STAGE_A(1, 1, tb);
    BAR; MFMA_Q1(aF, bFa, 0, 0); BAR;

    LOAD_B1(bFb, lB0, 1);
    BAR; MFMA_Q1(aF, bFb, 0, 1); BAR;

    LOAD_A(aF, lA0, 1);
    STAGE_B1(0, 0, tc);
    BAR; MFMA_Q1(aF, bFb, 1, 1); BAR;

    STAGE_B1(0, 1, tc);
    STAGE_A(0, 0, tc);
    VMCNT4;               // drain buf1's 6 (of 10)
    BAR; MFMA_Q1(aF, bFa, 1, 0); BAR;

    LOAD_A(aF, lA1, 0); LOAD_B1(bFa, lB1, 0);
    STAGE_A(0, 1, tc);
    BAR; MFMA_Q1(aF, bFa, 0, 0); BAR;

    LOAD_B1(bFb, lB1, 1);
    BAR; MFMA_Q1(aF, bFb, 0, 1); BAR;

    LOAD_A(aF, lA1, 1);
    STAGE_B1(1, 0, td);
    BAR; MFMA_Q1(aF, bFb, 1, 1); BAR;

    STAGE_B1(1, 1, td);
    STAGE_A(1, 0, td);
    VMCNT4;               // drain buf0's 6 (of 10)
    BAR; MFMA_Q1(aF, bFa, 1, 0); BAR;
  }

  { // final pair
    const int tb = nt - 1;
    LOAD_A(aF, lA0, 0); LOAD_B1(bFa, lB0, 0);
    STAGE_A(1, 1, tb);
    BAR; MFMA_Q1(aF, bFa, 0, 0); BAR;

    LOAD_B1(bFb, lB0, 1);
    BAR; MFMA_Q1(aF, bFb, 0, 1); BAR;

    LOAD_A(aF, lA0, 1);
    BAR; MFMA_Q1(aF, bFb, 1, 1); BAR;

    VMCNT0;
    BAR; MFMA_Q1(aF, bFa, 1, 0); BAR;

    LOAD_A(aF, lA1, 0); LOAD_B1(bFa, lB1, 0);
    BAR; MFMA_Q1(aF, bFa, 0, 0); BAR;

    LOAD_B1(bFb, lB1, 1);
    BAR; MFMA_Q1(aF, bFb, 0, 1); BAR;

    LOAD_A(aF, lA1, 1);
    BAR; MFMA_Q1(aF, bFb, 1, 1); BAR;

    MFMA_Q1(aF, bFa, 1, 0);
  }
}

// ---------------- fused prep: z<3 -> transpose+cast W; z==3 -> cast x ----------------
__global__ __launch_bounds__(256) void prep_kernel(
    const float* __restrict__ x,
    const float* __restrict__ Wq,
    const float* __restrict__ Wk,
    const float* __restrict__ Wv,
    __hip_bfloat16* __restrict__ xb,
    __hip_bfloat16* __restrict__ Wt3)
{
  const int tx = threadIdx.x, ty = threadIdx.y;  // (32,8)
  if (blockIdx.z == 3) {
    const int tid = ty * 32 + tx;
    const size_t base = ((size_t)blockIdx.y * 32 + blockIdx.x) * 8192;
#pragma unroll
    for (int p = 0; p < 8; p++) {
      const size_t i = base + p * 1024 + tid * 4;
      const float4 v = *(const float4*)(x + i);
      __hip_bfloat16 o[4] = {__float2bfloat16(v.x), __float2bfloat16(v.y),
                             __float2bfloat16(v.z), __float2bfloat16(v.w)};
      *(uint64_t*)(xb + i) = *(uint64_t*)o;
    }
    return;
  }
  const float* src = (blockIdx.z == 0) ? Wq : (blockIdx.z == 1) ? Wk : Wv;
  __hip_bfloat16* dst = Wt3 + (size_t)blockIdx.z * D_EMB * D_EMB;
  __shared__ __hip_bfloat16 tile[32][33];
  const int x0 = blockIdx.x * 32;  // e
  const int y0 = blockIdx.y * 32;  // d
#pragma unroll
  for (int i = 0; i < 32; i += 8)
    tile[ty + i][tx] = __float2bfloat16(src[(size_t)(y0 + ty + i) * D_EMB + (x0 + tx)]);
  __syncthreads();
#pragma unroll
  for (int i = 0; i < 32; i += 8)
    dst[(size_t)(x0 + ty + i) * D_EMB + (y0 + tx)] = tile[tx][ty + i];
}

// ---------------- QKV projections (per-tile 256^2, 8-phase) ----------------
// grid (32 m-tiles, 4 n-tiles, 3 mats), m fastest.
// z=0: Q[b][s][e], z=1: K[b][s][e], z=2: V transposed -> Vt[b][e][s]
__global__ __launch_bounds__(512, 2) void qkv_kernel(
    const __hip_bfloat16* __restrict__ xb,
    const __hip_bfloat16* __restrict__ Wt3,
    const float* __restrict__ bq,
    const float* __restrict__ bk,
    const float* __restrict__ bv,
    __hip_bfloat16* __restrict__ Q,
    __hip_bfloat16* __restrict__ Kb,
    __hip_bfloat16* __restrict__ Vt)
{
  const int mat = blockIdx.z;
  const int m0  = blockIdx.x * 256;
  const int n0  = blockIdx.y * 256;

  f32x4 acc[8][4];
  ZERO_ACC(acc);

  gemm256(xb + (size_t)m0 * D_EMB, D_EMB,
          Wt3 + (size_t)mat * D_EMB * D_EMB + (size_t)n0 * D_EMB, D_EMB,
          D_EMB, acc);

  const float* bias = (mat == 0) ? bq : (mat == 1) ? bk : bv;

  const int t = threadIdx.x;
  const int wave = t >> 6, lane = t & 63;
  const int quad = lane >> 4, lr = lane & 15;
  const int wr = wave >> 2, wc = wave & 3;

#pragma unroll
  for (int i = 0; i < 8; i++) {
#pragma unroll
    for (int j = 0; j < 4; j++) {
      const int n = n0 + wc * 64 + j * 16 + lr;
      const float bb = bias[n];
      const int mbase = m0 + wr * 128 + i * 16 + quad * 4;
      if (mat == 2) {
        const int b = mbase >> 11, s = mbase & 2047;
        __hip_bfloat16 pk[4];
#pragma unroll
        for (int r = 0; r < 4; r++) pk[r] = __float2bfloat16(acc[i][j][r] + bb);
        *(uint64_t*)&Vt[(size_t)b * D_EMB * SEQ + (size_t)n * SEQ + s] = *(uint64_t*)pk;
      } else {
        __hip_bfloat16* dst = (mat == 0) ? Q : Kb;
#pragma unroll
        for (int r = 0; r < 4; r++)
          dst[(size_t)(mbase + r) * D_EMB + n] = __float2bfloat16(acc[i][j][r] + bb);
      }
    }
  }
}

// ---------------- scores = Q @ K^T * scale (fp16 out) ----------------
__global__ __launch_bounds__(512, 2) void scores_kernel(
    const __hip_bfloat16* __restrict__ Q,
    const __hip_bfloat16* __restrict__ Kb,
    __half* __restrict__ Sc)
{
  const int b  = blockIdx.z;
  const int m0 = blockIdx.y * 256;  // s_q
  const int n0 = blockIdx.x * 256;  // s_k

  f32x4 acc[8][4];
  ZERO_ACC(acc);

  gemm256(Q  + (size_t)b * SEQ * D_EMB + (size_t)m0 * D_EMB, D_EMB,
          Kb + (size_t)b * SEQ * D_EMB + (size_t)n0 * D_EMB, D_EMB,
          D_EMB, acc);

  __half* out = Sc + (size_t)b * SEQ * SEQ;
  const float scale = 0.03125f;  // 1/sqrt(1024)

  const int t = threadIdx.x;
  const int wave = t >> 6, lane = t & 63;
  const int quad = lane >> 4, lr = lane & 15;
  const int wr = wave >> 2, wc = wave & 3;

#pragma unroll
  for (int i = 0; i < 8; i++)
#pragma unroll
    for (int j = 0; j < 4; j++) {
      const int n = n0 + wc * 64 + j * 16 + lr;
#pragma unroll
      for (int r = 0; r < 4; r++) {
        const int m = m0 + wr * 128 + i * 16 + quad * 4 + r;
        out[(size_t)m * SEQ + n] = __float2half(acc[i][j][r] * scale);
      }
    }
}

// ---------------- row softmax: fp16 scores -> bf16 probs (16B vectorized) ----------------
__global__ __launch_bounds__(256) void softmax_kernel(
    const __half* __restrict__ Sc, __hip_bfloat16* __restrict__ P)
{
  const int row = blockIdx.x;  // 0..8191
  const __half* src = Sc + (size_t)row * SEQ;
  const int t = threadIdx.x;
  const int wave = t >> 6, lane = t & 63;

  const short8 raw = *(const short8*)(src + t * 8);
  float v[8];
#pragma unroll
  for (int i = 0; i < 8; i++) {
    const short si = raw[i];
    __half h;
    memcpy(&h, &si, sizeof(h));
    v[i] = __half2float(h);
  }

  float m = v[0];
#pragma unroll
  for (int i = 1; i < 8; i++) m = fmaxf(m, v[i]);
#pragma unroll
  for (int o = 32; o > 0; o >>= 1) m = fmaxf(m, __shfl_xor(m, o));

  __shared__ float redm[4];
  __shared__ float reds[4];
  if (lane == 0) redm[wave] = m;
  __syncthreads();
  m = fmaxf(fmaxf(redm[0], redm[1]), fmaxf(redm[2], redm[3]));

  float e[8], s = 0.f;
#pragma unroll
  for (int i = 0; i < 8; i++) { e[i] = __expf(v[i] - m); s += e[i]; }
#pragma unroll
  for (int o = 32; o > 0; o >>= 1) s += __shfl_xor(s, o);
  if (lane == 0) reds[wave] = s;
  __syncthreads();
  s = reds[0] + reds[1] + reds[2] + reds[3];

  const float inv = 1.f / s;
  short8 outp;
#pragma unroll
  for (int i = 0; i < 8; i++) {
    const __hip_bfloat16 b = __float2bfloat16(e[i] * inv);
    short sb;
    memcpy(&sb, &b, sizeof(sb));
    outp[i] = sb;
  }
  *(short8*)(P + (size_t)row * SEQ + t * 8) = outp;
}

// ---------------- out(fp32) = P @ V  (256x128 tiles -> 256 blocks, 1 round) ----------------
__global__ __launch_bounds__(512, 2) void pv_kernel(
    const __hip_bfloat16* __restrict__ P,
    const __hip_bfloat16* __restrict__ Vt,
    float* __restrict__ out)
{
  const int b  = blockIdx.z;
  const int m0 = blockIdx.y * 256;  // s_q
  const int n0 = blockIdx.x * 128;  // e

  f32x4 acc[8][2];
  ZERO_ACC2(acc);

  gemm256x128(P  + (size_t)b * SEQ * SEQ   + (size_t)m0 * SEQ, SEQ,
              Vt + (size_t)b * D_EMB * SEQ + (size_t)n0 * SEQ, SEQ,
              SEQ, acc);

  float* o = out + (size_t)b * SEQ * D_EMB;

  const int t = threadIdx.x;
  const int wave = t >> 6, lane = t & 63;
  const int quad = lane >> 4, lr = lane & 15;
  const int wr = wave >> 2, wc = wave & 3;

#pragma unroll
  for (int i = 0; i < 8; i++)
#pragma unroll
    for (int j = 0; j < 2; j++) {
      const int n = n0 + wc * 32 + j * 16 + lr;
#pragma unroll
      for (int r = 0; r < 4; r++) {
        const int m = m0 + wr * 128 + i * 16 + quad * 4 + r;
        o[(size_t)m * D_EMB + n] = acc[i][j][r];
      }
    }
}

extern "C" void kernel_launch(void* const* d_in, const int* in_sizes, int n_in,
                              void* d_out, int out_size, void* d_ws, size_t ws_size,
                              hipStream_t stream) {
  const float* x  = (const float*)d_in[0];
  const float* Wq = (const float*)d_in[1];
  const float* bq = (const float*)d_in[2];
  const float* Wk = (const float*)d_in[3];
  const float* bk = (const float*)d_in[4];
  const float* Wv = (const float*)d_in[5];
  const float* bv = (const float*)d_in[6];
  float* out = (float*)d_out;

  char* ws = (char*)d_ws;
  __hip_bfloat16* xb  = (__hip_bfloat16*)(ws);
  __hip_bfloat16* Wt3 = (__hip_bfloat16*)(ws + 16777216);
  __hip_bfloat16* Q   = (__hip_bfloat16*)(ws + 23068672);
  __hip_bfloat16* Kb  = (__hip_bfloat16*)(ws + 39845888);
  __hip_bfloat16* Vt  = (__hip_bfloat16*)(ws + 56623104);
  __half*         Sc  = (__half*)        (ws + 73400320);   // 32 MB fp16
  __hip_bfloat16* P   = (__hip_bfloat16*)(ws + 140509184);
  // total = 140509184 + 33554432 = 174,063,616 bytes (~166 MB)

  prep_kernel  <<<dim3(32, 32, 4), dim3(32, 8), 0, stream>>>(x, Wq, Wk, Wv, xb, Wt3);
  qkv_kernel   <<<dim3(32, 4, 3),  512,        0, stream>>>(xb, Wt3, bq, bk, bv, Q, Kb, Vt);
  scores_kernel<<<dim3(8, 8, 4),   512,        0, stream>>>(Q, Kb, Sc);
  softmax_kernel<<<dim3(8192),     256,        0, stream>>>(Sc, P);
  pv_kernel    <<<dim3(8, 8, 4),   512,        0, stream>>>(P, Vt, out);
}